// Round 4
// baseline (2468.761 us; speedup 1.0000x reference)
//
#include <hip/hip_runtime.h>

#define B_ 2
#define S_ 2048
#define D_ 768
#define H_ 12
#define DK_ 64
#define BH_ (B_*H_)
#define NEGV (-1e9f)
#define SCALE 0.125f
#define MINIT (-1e30f)

typedef unsigned short u16;

__device__ __forceinline__ float bf2f(u16 u){
  union { unsigned int i; float f; } v; v.i = ((unsigned int)u) << 16; return v.f;
}
__device__ __forceinline__ u16 f2bf(float f){
  union { float f; unsigned int i; } v; v.f = f;
  unsigned int x = v.i;
  return (u16)((x + 0x7FFFu + ((x >> 16) & 1u)) >> 16);
}
__device__ __forceinline__ void f4a(const float* p, float* a){
  float4 v = *(const float4*)p; a[0]=v.x; a[1]=v.y; a[2]=v.z; a[3]=v.w;
}

// ---------------- GEMM: C[r,c] = sum_k X[r,k]*W[c,k] + bias[c], M=4096,N=768,K=768
// XBF16: X is bf16 (ctx ws) else f32. HEADSPLIT: out = bf16 ws head-split; else out = f32 plain.
template<bool XBF16, bool HEADSPLIT>
__device__ __forceinline__ void gemm64(const void* __restrict__ Xp_, const float* __restrict__ W,
                                       const float* __restrict__ bias, void* __restrict__ outp)
{
  const int row0 = blockIdx.x * 64;
  const int col0 = blockIdx.y * 64;
  const int tx = threadIdx.x, ty = threadIdx.y;
  const int tid = ty*16 + tx;

  __shared__ float As[16][68];
  __shared__ float Bs[16][68];

  float acc[4][4] = {};

  const int mrow = tid >> 2;        // 0..63
  const int kq   = (tid & 3) * 4;   // 0,4,8,12
  const float* wp = W + (size_t)(col0 + mrow) * D_ + kq;

  for (int k0 = 0; k0 < D_; k0 += 16) {
    __syncthreads();
    if constexpr (XBF16) {
      const u16* X = (const u16*)Xp_;
      ushort4 ua = *(const ushort4*)(X + (size_t)(row0 + mrow) * D_ + kq + k0);
      As[kq+0][mrow]=bf2f(ua.x); As[kq+1][mrow]=bf2f(ua.y); As[kq+2][mrow]=bf2f(ua.z); As[kq+3][mrow]=bf2f(ua.w);
    } else {
      const float* X = (const float*)Xp_;
      float4 fa = *(const float4*)(X + (size_t)(row0 + mrow) * D_ + kq + k0);
      As[kq+0][mrow]=fa.x; As[kq+1][mrow]=fa.y; As[kq+2][mrow]=fa.z; As[kq+3][mrow]=fa.w;
    }
    float4 fb = *(const float4*)(wp + k0);
    Bs[kq+0][mrow]=fb.x; Bs[kq+1][mrow]=fb.y; Bs[kq+2][mrow]=fb.z; Bs[kq+3][mrow]=fb.w;
    __syncthreads();
    #pragma unroll
    for (int kk=0; kk<16; kk++){
      float a[4], b[4];
      f4a(&As[kk][ty*4], a);
      f4a(&Bs[kk][tx*4], b);
      #pragma unroll
      for (int i=0;i<4;i++)
        #pragma unroll
        for (int j=0;j<4;j++)
          acc[i][j] += a[i]*b[j];
    }
  }

  float bb[4];
  #pragma unroll
  for (int j=0;j<4;j++) bb[j] = bias[col0 + tx*4 + j];

  if constexpr (HEADSPLIT) {
    u16* out = (u16*)outp;
    const int h = col0 >> 6;       // tile width 64 == DK -> single head per tile
    const int batch = row0 >> 11;  // tile rows never cross batch boundary
    #pragma unroll
    for (int i=0;i<4;i++){
      int r = row0 + ty*4 + i;
      int s = r & (S_-1);
      ushort4 w;
      w.x = f2bf(acc[i][0]+bb[0]); w.y = f2bf(acc[i][1]+bb[1]);
      w.z = f2bf(acc[i][2]+bb[2]); w.w = f2bf(acc[i][3]+bb[3]);
      *(ushort4*)(out + ((size_t)(batch*H_ + h)*S_ + s)*DK_ + tx*4) = w;
    }
  } else {
    float* out = (float*)outp;
    #pragma unroll
    for (int i=0;i<4;i++){
      int r = row0 + ty*4 + i;
      *(float4*)(out + (size_t)r*D_ + col0 + tx*4) =
          make_float4(acc[i][0]+bb[0], acc[i][1]+bb[1], acc[i][2]+bb[2], acc[i][3]+bb[3]);
    }
  }
}

__global__ __launch_bounds__(256) void proj_qkv(
    const float* __restrict__ Xq, const float* __restrict__ Xk, const float* __restrict__ Xv,
    const float* __restrict__ Wq, const float* __restrict__ bq,
    const float* __restrict__ Wk, const float* __restrict__ bk,
    const float* __restrict__ Wv, const float* __restrict__ bv,
    u16* __restrict__ qkv)
{
  const int z = blockIdx.z;
  const float* X = (z==0)?Xq:(z==1)?Xk:Xv;
  const float* W = (z==0)?Wq:(z==1)?Wk:Wv;
  const float* bia = (z==0)?bq:(z==1)?bk:bv;
  u16* out = qkv + (size_t)z * ((size_t)BH_*S_*DK_);
  gemm64<false, true>((const void*)X, W, bia, (void*)out);
}

__global__ __launch_bounds__(256) void proj_o(
    const u16* __restrict__ Xc, const float* __restrict__ Wo, const float* __restrict__ bo,
    float* __restrict__ out)
{
  gemm64<true, false>((const void*)Xc, Wo, bo, (void*)out);
}

// ---------------- attention ----------------
__device__ __forceinline__ void load_tile64(float (*dst)[68], const u16* __restrict__ src, int r0, int tid){
  #pragma unroll
  for (int i=0;i<4;i++){
    int idx = tid + i*256;
    int row = idx >> 4, c = (idx & 15) * 4;
    ushort4 u = *(const ushort4*)(src + (size_t)(r0+row)*DK_ + c);
    dst[row][c+0]=bf2f(u.x); dst[row][c+1]=bf2f(u.y); dst[row][c+2]=bf2f(u.z); dst[row][c+3]=bf2f(u.w);
  }
}

__device__ __forceinline__ void qk_tile(const float (*Qs)[68], const float (*Ks)[68],
                                        int ty, int tx, float sv[4][4]){
  #pragma unroll
  for (int i=0;i<4;i++)
    #pragma unroll
    for (int j=0;j<4;j++) sv[i][j]=0.f;
  #pragma unroll
  for (int d=0; d<64; d+=4){
    float qa[4][4], kb[4][4];
    #pragma unroll
    for (int i=0;i<4;i++) f4a(&Qs[ty*4+i][d], qa[i]);
    #pragma unroll
    for (int j=0;j<4;j++) f4a(&Ks[tx*4+j][d], kb[j]);
    #pragma unroll
    for (int i=0;i<4;i++)
      #pragma unroll
      for (int j=0;j<4;j++)
        #pragma unroll
        for (int c=0;c<4;c++)
          sv[i][j] += qa[i][c]*kb[j][c];
  }
}

__global__ __launch_bounds__(256) void attn(const u16* __restrict__ qkv, const int* __restrict__ mask,
                                            float* __restrict__ la, u16* __restrict__ ctx)
{
  const int bh = blockIdx.y;
  const int q0 = blockIdx.x * 64;
  const int b = bh / H_;
  const int h = bh - b*H_;
  const u16* Qp = qkv + (size_t)bh * S_ * DK_;
  const u16* Kp = qkv + (size_t)(BH_ + bh) * S_ * DK_;
  const u16* Vp = qkv + (size_t)(2*BH_ + bh) * S_ * DK_;
  const int* Mp = mask + (size_t)b * S_ * S_;
  const int tx = threadIdx.x, ty = threadIdx.y;
  const int tid = ty*16 + tx;

  __shared__ float Qs[64][68];
  __shared__ float Ks[64][68];
  __shared__ float Vs[64][68];
  __shared__ float redM[64][17];
  __shared__ float redL[64][17];

  load_tile64(Qs, Qp, q0, tid);

  float mt[4], lt[4];
  #pragma unroll
  for (int i=0;i<4;i++){ mt[i] = MINIT; lt[i] = 0.f; }

  // ---- pass A: per-lane online softmax stats over this lane's 4-col chunks ----
  for (int j0=0; j0<S_; j0+=64){
    __syncthreads();
    load_tile64(Ks, Kp, j0, tid);
    __syncthreads();
    float sv[4][4];
    qk_tile(Qs, Ks, ty, tx, sv);
    #pragma unroll
    for (int i=0;i<4;i++){
      const int qi = q0 + ty*4 + i;
      int4 mk = *(const int4*)(Mp + (size_t)qi*S_ + j0 + tx*4);
      int m0[4] = {mk.x, mk.y, mk.z, mk.w};
      float s[4];
      #pragma unroll
      for (int j=0;j<4;j++) s[j] = m0[j] ? sv[i][j]*SCALE : NEGV;
      float cm = fmaxf(fmaxf(s[0],s[1]), fmaxf(s[2],s[3]));
      float mn = fmaxf(mt[i], cm);
      lt[i] = lt[i]*__expf(fminf(mt[i]-mn, 0.f))
            + __expf(fminf(s[0]-mn,0.f)) + __expf(fminf(s[1]-mn,0.f))
            + __expf(fminf(s[2]-mn,0.f)) + __expf(fminf(s[3]-mn,0.f));
      mt[i] = mn;
    }
  }

  // ---- combine the 16 lanes of each row via LDS (deterministic, no shuffles) ----
  #pragma unroll
  for (int i=0;i<4;i++){ redM[ty*4+i][tx] = mt[i]; redL[ty*4+i][tx] = lt[i]; }
  __syncthreads();
  float ml[4];
  #pragma unroll
  for (int i=0;i<4;i++){
    const int r = ty*4 + i;
    float m = MINIT, l = 0.f;
    for (int t=0; t<16; t++){
      float m2 = redM[r][t], l2 = redL[r][t];
      float mn = fmaxf(m, m2);
      l = l*__expf(fminf(m-mn,0.f)) + l2*__expf(fminf(m2-mn,0.f));
      m = mn;
    }
    ml[i] = m + __logf(fmaxf(l, 1e-30f));
  }

  // ---- pass B: recompute scores, emit log_attn, accumulate P·V ----
  float o[4][4] = {};

  for (int j0=0; j0<S_; j0+=64){
    __syncthreads();              // redM/redL reads + previous PV reads all done
    load_tile64(Ks, Kp, j0, tid);
    load_tile64(Vs, Vp, j0, tid);
    __syncthreads();
    float sv[4][4];
    qk_tile(Qs, Ks, ty, tx, sv);
    float pv[4][4];
    #pragma unroll
    for (int i=0;i<4;i++){
      const int qi = q0 + ty*4 + i;
      int4 mk = *(const int4*)(Mp + (size_t)qi*S_ + j0 + tx*4);
      int m0[4] = {mk.x, mk.y, mk.z, mk.w};
      float lv[4];
      #pragma unroll
      for (int j=0;j<4;j++){
        float s = m0[j] ? sv[i][j]*SCALE : NEGV;
        lv[j] = fminf(s - ml[i], 0.f);   // mathematically <=0; clamp forces p<=1
        pv[i][j] = __expf(lv[j]);
      }
      *(float4*)(la + ((size_t)bh*S_ + qi)*S_ + j0 + tx*4) =
          make_float4(lv[0], lv[1], lv[2], lv[3]);
    }
    __syncthreads();              // all QK reads of Ks done
    #pragma unroll
    for (int i=0;i<4;i++){
      *(float4*)&Ks[ty*4+i][tx*4] = make_float4(pv[i][0], pv[i][1], pv[i][2], pv[i][3]);
    }
    __syncthreads();              // P fully staged in Ks
    #pragma unroll
    for (int c4=0; c4<64; c4+=4){
      float pa[4][4], vv[4][4];
      #pragma unroll
      for (int i=0;i<4;i++) f4a(&Ks[ty*4+i][c4], pa[i]);
      #pragma unroll
      for (int cc=0;cc<4;cc++) f4a(&Vs[c4+cc][tx*4], vv[cc]);
      #pragma unroll
      for (int i=0;i<4;i++)
        #pragma unroll
        for (int j=0;j<4;j++)
          #pragma unroll
          for (int cc=0;cc<4;cc++)
            o[i][j] += pa[i][cc]*vv[cc][j];
    }
  }
  #pragma unroll
  for (int i=0;i<4;i++){
    const int qi = q0 + ty*4 + i;
    ushort4 w;
    w.x = f2bf(o[i][0]); w.y = f2bf(o[i][1]); w.z = f2bf(o[i][2]); w.w = f2bf(o[i][3]);
    *(ushort4*)(ctx + ((size_t)b*S_ + qi)*D_ + h*DK_ + tx*4) = w;
  }
}

extern "C" void kernel_launch(void* const* d_in, const int* in_sizes, int n_in,
                              void* d_out, int out_size, void* d_ws, size_t ws_size,
                              hipStream_t stream)
{
  const float* query = (const float*)d_in[0];
  const float* key   = (const float*)d_in[1];
  const float* value = (const float*)d_in[2];
  const int* mask    = (const int*)d_in[3];
  const float* Wq = (const float*)d_in[4];  const float* bq = (const float*)d_in[5];
  const float* Wk = (const float*)d_in[6];  const float* bk = (const float*)d_in[7];
  const float* Wv = (const float*)d_in[8];  const float* bv = (const float*)d_in[9];
  const float* Wo = (const float*)d_in[10]; const float* bo = (const float*)d_in[11];

  float* out = (float*)d_out;                      // [B,S,D] f32
  float* la  = out + (size_t)B_*S_*D_;             // [B,H,S,S] f32
  u16* qkvws = (u16*)d_ws;                         // [3][BH,S,DK] bf16
  u16* ctx = qkvws + (size_t)3*BH_*S_*DK_;         // [B,S,D] bf16

  dim3 blk(16,16,1);
  proj_qkv<<<dim3(64,12,3), blk, 0, stream>>>(query,key,value,Wq,bq,Wk,bk,Wv,bv,qkvws);
  attn<<<dim3(S_/64, BH_,1), blk, 0, stream>>>(qkvws, mask, la, ctx);
  proj_o<<<dim3(64,12,1), blk, 0, stream>>>(ctx, Wo, bo, out);
}